// Round 3
// baseline (1014.296 us; speedup 1.0000x reference)
//
#include <hip/hip_runtime.h>
#include <cstdint>
#include <cstddef>

#define BATCH 16

static constexpr int NN0 = 32768, NN1 = 8192, NN2 = 2048, NN3 = 512, NN4 = 128;

// ---------------- fused weight transposes: W (CO,K) -> Wt (K,CO) ----------------
struct TD { const float* W; float* Wt; int CO, K, off; };
struct TA { TD d[8]; int total; };

__global__ __launch_bounds__(256) void transpose_all(TA a) {
    int i = blockIdx.x * 256 + threadIdx.x;
    if (i >= a.total) return;
    #pragma unroll
    for (int j = 0; j < 8; ++j) {
        const TD t = a.d[j];
        if (i >= t.off && i < t.off + t.CO * t.K) {
            int e = i - t.off, c = e / t.K, k = e - c * t.K;
            t.Wt[k * t.CO + c] = t.W[e];
            return;
        }
    }
}

// ---------------- conv v3: lane=vertex, wave=16-channel group, W via scalar loads ----
// x: (B,N,CIN), idx: (N,9), Wt: (9*CIN, COUT), out: (B,N,COUT)
template<int CIN, int COUT, bool ELU>
__global__ __launch_bounds__(256) void conv_v3(const float* __restrict__ x,
                                               const int* __restrict__ idx,
                                               const float* __restrict__ Wt,
                                               const float* __restrict__ bias,
                                               float* __restrict__ out,
                                               int N) {
    static_assert(COUT % 16 == 0, "COUT multiple of 16");
    constexpr int QG    = COUT / 16;       // 16-channel groups
    static_assert(QG <= 4 && 4 % QG == 0, "QG in {1,2,4}");
    constexpr int VSETS = 4 / QG;          // vertex sets of 64 per block
    constexpr int VPB   = 64 * VSETS;
    constexpr int GS    = CIN + 4;         // pad: stride == 4 mod 32 banks -> conflict-free b128
    constexpr int CQ    = CIN / 4;

    __shared__ float g[VPB][GS];
    __shared__ int   nbr[VPB][9];

    const int b  = blockIdx.y;
    const int v0 = blockIdx.x * VPB;
    const float* __restrict__ xb = x + (size_t)b * N * CIN;

    for (int t = threadIdx.x; t < VPB * 9; t += 256)
        nbr[t / 9][t % 9] = idx[(size_t)v0 * 9 + t];

    const int wv   = __builtin_amdgcn_readfirstlane(threadIdx.x >> 6); // uniform wave id
    const int lane = threadIdx.x & 63;
    const int vset = wv / QG;              // which 64-vertex set
    const int qg   = wv % QG;              // which 16 output channels
    const int vloc = vset * 64 + lane;

    float4 acc[4];
    #pragma unroll
    for (int q = 0; q < 4; ++q) acc[q] = make_float4(0.f, 0.f, 0.f, 0.f);

    for (int s = 0; s < 9; ++s) {
        __syncthreads();                   // iter0: nbr ready; later: g consumed
        constexpr int GSLOTS = VPB * CQ;   // float4 slots
        static_assert(GSLOTS % 256 == 0, "staging divisibility");
        #pragma unroll
        for (int p = 0; p < GSLOTS / 256; ++p) {
            const int slot = p * 256 + threadIdx.x;
            const int v = slot / CQ, q = slot - v * CQ;
            const float4 t4 = *reinterpret_cast<const float4*>(
                xb + (size_t)nbr[v][s] * CIN + q * 4);
            *reinterpret_cast<float4*>(&g[v][q * 4]) = t4;
        }
        __syncthreads();

        const float* __restrict__ wbase = Wt + (size_t)s * CIN * COUT + qg * 16;
        #pragma unroll
        for (int k4 = 0; k4 < CQ; ++k4) {
            const float4 gv = *reinterpret_cast<const float4*>(&g[vloc][k4 * 4]);
            #pragma unroll
            for (int kk = 0; kk < 4; ++kk) {
                const float* __restrict__ wr = wbase + (size_t)(k4 * 4 + kk) * COUT;
                const float4 w0 = *reinterpret_cast<const float4*>(wr);
                const float4 w1 = *reinterpret_cast<const float4*>(wr + 4);
                const float4 w2 = *reinterpret_cast<const float4*>(wr + 8);
                const float4 w3 = *reinterpret_cast<const float4*>(wr + 12);
                const float gk = (kk == 0) ? gv.x : (kk == 1) ? gv.y : (kk == 2) ? gv.z : gv.w;
                acc[0].x += gk * w0.x; acc[0].y += gk * w0.y; acc[0].z += gk * w0.z; acc[0].w += gk * w0.w;
                acc[1].x += gk * w1.x; acc[1].y += gk * w1.y; acc[1].z += gk * w1.z; acc[1].w += gk * w1.w;
                acc[2].x += gk * w2.x; acc[2].y += gk * w2.y; acc[2].z += gk * w2.z; acc[2].w += gk * w2.w;
                acc[3].x += gk * w3.x; acc[3].y += gk * w3.y; acc[3].z += gk * w3.z; acc[3].w += gk * w3.w;
            }
        }
    }

    float* __restrict__ orow = out + ((size_t)b * N + v0 + vloc) * COUT + qg * 16;
    #pragma unroll
    for (int q = 0; q < 4; ++q) {
        const float4 bv = *reinterpret_cast<const float4*>(bias + qg * 16 + q * 4);
        float4 a = acc[q];
        a.x += bv.x; a.y += bv.y; a.z += bv.z; a.w += bv.w;
        if constexpr (ELU) {
            a.x = a.x > 0.f ? a.x : expm1f(a.x);
            a.y = a.y > 0.f ? a.y : expm1f(a.y);
            a.z = a.z > 0.f ? a.z : expm1f(a.z);
            a.w = a.w > 0.f ? a.w : expm1f(a.w);
        }
        *reinterpret_cast<float4*>(orow + q * 4) = a;
    }
}

// ---------------- first conv (CIN=3, COUT=32): stage all 9 neighbors once ----------------
__global__ __launch_bounds__(256) void conv0_v3(const float* __restrict__ x,
                                                const int* __restrict__ idx,
                                                const float* __restrict__ Wt,   // (27,32)
                                                const float* __restrict__ bias,
                                                float* __restrict__ out,
                                                int N) {
    constexpr int VPB = 128;               // QG=2, 2 vertex sets
    constexpr int GS  = 36;                // 9 float4 slots per vertex
    __shared__ float g[VPB][GS];

    const int b  = blockIdx.y;
    const int v0 = blockIdx.x * VPB;
    const float* __restrict__ xb = x + (size_t)b * N * 3;

    // stage: one (v,s) per slot; read 3 floats, pack to float4
    for (int slot = threadIdx.x; slot < VPB * 9; slot += 256) {
        const int v = slot / 9, s = slot - v * 9;
        const int n = idx[(size_t)v0 * 9 + slot];
        const float* p = xb + (size_t)n * 3;
        float4 t4; t4.x = p[0]; t4.y = p[1]; t4.z = p[2]; t4.w = 0.f;
        *reinterpret_cast<float4*>(&g[v][s * 4]) = t4;
    }
    __syncthreads();

    const int wv   = __builtin_amdgcn_readfirstlane(threadIdx.x >> 6);
    const int lane = threadIdx.x & 63;
    const int vset = wv >> 1;
    const int qg   = wv & 1;
    const int vloc = vset * 64 + lane;

    float4 acc[4];
    #pragma unroll
    for (int q = 0; q < 4; ++q) acc[q] = make_float4(0.f, 0.f, 0.f, 0.f);

    #pragma unroll
    for (int s = 0; s < 9; ++s) {
        const float4 gv = *reinterpret_cast<const float4*>(&g[vloc][s * 4]);
        #pragma unroll
        for (int c = 0; c < 3; ++c) {
            const float* __restrict__ wr = Wt + (size_t)(s * 3 + c) * 32 + qg * 16;
            const float4 w0 = *reinterpret_cast<const float4*>(wr);
            const float4 w1 = *reinterpret_cast<const float4*>(wr + 4);
            const float4 w2 = *reinterpret_cast<const float4*>(wr + 8);
            const float4 w3 = *reinterpret_cast<const float4*>(wr + 12);
            const float gk = (c == 0) ? gv.x : (c == 1) ? gv.y : gv.z;
            acc[0].x += gk * w0.x; acc[0].y += gk * w0.y; acc[0].z += gk * w0.z; acc[0].w += gk * w0.w;
            acc[1].x += gk * w1.x; acc[1].y += gk * w1.y; acc[1].z += gk * w1.z; acc[1].w += gk * w1.w;
            acc[2].x += gk * w2.x; acc[2].y += gk * w2.y; acc[2].z += gk * w2.z; acc[2].w += gk * w2.w;
            acc[3].x += gk * w3.x; acc[3].y += gk * w3.y; acc[3].z += gk * w3.z; acc[3].w += gk * w3.w;
        }
    }

    float* __restrict__ orow = out + ((size_t)b * N + v0 + vloc) * 32 + qg * 16;
    #pragma unroll
    for (int q = 0; q < 4; ++q) {
        const float4 bv = *reinterpret_cast<const float4*>(bias + qg * 16 + q * 4);
        float4 a = acc[q];
        a.x += bv.x; a.y += bv.y; a.z += bv.z; a.w += bv.w;
        a.x = a.x > 0.f ? a.x : expm1f(a.x);
        a.y = a.y > 0.f ? a.y : expm1f(a.y);
        a.z = a.z > 0.f ? a.z : expm1f(a.z);
        a.w = a.w > 0.f ? a.w : expm1f(a.w);
        *reinterpret_cast<float4*>(orow + q * 4) = a;
    }
}

// ---------------- final conv (CIN=32, COUT=3): W used untransposed (3,288) ----------------
__global__ __launch_bounds__(256) void out_conv_v3(const float* __restrict__ x,
                                                   const int* __restrict__ idx,
                                                   const float* __restrict__ W,   // (3,288)
                                                   const float* __restrict__ bias,
                                                   float* __restrict__ out,
                                                   int N) {
    constexpr int VPB = 256;
    constexpr int GS  = 36;
    __shared__ float g[VPB][GS];
    __shared__ int   nbr[VPB][9];

    const int b  = blockIdx.y;
    const int v0 = blockIdx.x * VPB;
    const float* __restrict__ xb = x + (size_t)b * N * 32;

    for (int t = threadIdx.x; t < VPB * 9; t += 256)
        nbr[t / 9][t % 9] = idx[(size_t)v0 * 9 + t];

    const int vloc = threadIdx.x;
    float a0 = 0.f, a1 = 0.f, a2 = 0.f;

    for (int s = 0; s < 9; ++s) {
        __syncthreads();
        #pragma unroll
        for (int p = 0; p < 8; ++p) {   // VPB*8 float4 slots / 256 threads
            const int slot = p * 256 + threadIdx.x;
            const int v = slot / 8, q = slot - v * 8;
            const float4 t4 = *reinterpret_cast<const float4*>(
                xb + (size_t)nbr[v][s] * 32 + q * 4);
            *reinterpret_cast<float4*>(&g[v][q * 4]) = t4;
        }
        __syncthreads();
        #pragma unroll
        for (int k4 = 0; k4 < 8; ++k4) {
            const float4 gv = *reinterpret_cast<const float4*>(&g[vloc][k4 * 4]);
            const float4 w0 = *reinterpret_cast<const float4*>(W +   0 + s * 32 + k4 * 4);
            const float4 w1 = *reinterpret_cast<const float4*>(W + 288 + s * 32 + k4 * 4);
            const float4 w2 = *reinterpret_cast<const float4*>(W + 576 + s * 32 + k4 * 4);
            a0 += gv.x * w0.x + gv.y * w0.y + gv.z * w0.z + gv.w * w0.w;
            a1 += gv.x * w1.x + gv.y * w1.y + gv.z * w1.z + gv.w * w1.w;
            a2 += gv.x * w2.x + gv.y * w2.y + gv.z * w2.z + gv.w * w2.w;
        }
    }

    float* o = out + ((size_t)b * N + v0 + vloc) * 3;
    o[0] = a0 + bias[0]; o[1] = a1 + bias[1]; o[2] = a2 + bias[2];
}

// ---------------- pool: out[b,r,:] = sum_{j<3} val[3r+j] * x[b, col[3r+j], :] ----------------
template<int C>
__global__ __launch_bounds__(256) void pool_kernel(const float* __restrict__ x,
                                                   const int* __restrict__ col,
                                                   const float* __restrict__ val,
                                                   float* __restrict__ out,
                                                   int Nout, int Nin) {
    constexpr int CQ = C / 4;
    const int q = blockIdx.x * 256 + threadIdx.x;
    if (q >= BATCH * Nout * CQ) return;
    const int cq = q % CQ;
    const int r  = (q / CQ) % Nout;
    const int b  = q / (CQ * Nout);
    float ax = 0.f, ay = 0.f, az = 0.f, aw = 0.f;
    #pragma unroll
    for (int j = 0; j < 3; ++j) {
        const int   c0 = col[3 * r + j];
        const float vl = val[3 * r + j];
        const float4 xv = *reinterpret_cast<const float4*>(
            x + ((size_t)b * Nin + c0) * C + cq * 4);
        ax += vl * xv.x; ay += vl * xv.y; az += vl * xv.z; aw += vl * xv.w;
    }
    float4 o; o.x = ax; o.y = ay; o.z = az; o.w = aw;
    *reinterpret_cast<float4*>(out + ((size_t)b * Nout + r) * C + cq * 4) = o;
}

// ---------------- encoder FC: z = sigmoid(h @ fcW^T + fcb), h (16,8192) ----------------
__global__ __launch_bounds__(256) void fc_enc_kernel(const float* __restrict__ h,
                                                     const float* __restrict__ W,   // (256, 8192)
                                                     const float* __restrict__ bias,
                                                     float* __restrict__ z,
                                                     float* __restrict__ out_z,
                                                     float* __restrict__ out_mu) {
    const int l = blockIdx.x;
    const float* __restrict__ wr = W + (size_t)l * 8192;
    float acc[BATCH];
    #pragma unroll
    for (int b = 0; b < BATCH; ++b) acc[b] = 0.f;
    for (int k = threadIdx.x * 4; k < 8192; k += 256 * 4) {
        const float4 w4 = *reinterpret_cast<const float4*>(wr + k);
        #pragma unroll
        for (int b = 0; b < BATCH; ++b) {
            const float4 h4 = *reinterpret_cast<const float4*>(h + (size_t)b * 8192 + k);
            acc[b] += w4.x * h4.x + w4.y * h4.y + w4.z * h4.z + w4.w * h4.w;
        }
    }
    __shared__ float red[BATCH][4];
    const int wid = threadIdx.x >> 6, lane = threadIdx.x & 63;
    #pragma unroll
    for (int b = 0; b < BATCH; ++b) {
        float v = acc[b];
        for (int off = 32; off; off >>= 1) v += __shfl_down(v, off);
        if (lane == 0) red[b][wid] = v;
    }
    __syncthreads();
    if (threadIdx.x < BATCH) {
        const int b = threadIdx.x;
        float s = red[b][0] + red[b][1] + red[b][2] + red[b][3] + bias[l];
        s = 1.f / (1.f + expf(-s));
        z[b * 256 + l]      = s;
        out_z[b * 256 + l]  = s;
        out_mu[b * 256 + l] = s;
    }
}

// ---------------- decoder FC: h = z @ dfcW^T + dfcb -> (16, 8192) ----------------
__global__ __launch_bounds__(256) void fc_dec_kernel(const float* __restrict__ z,   // (16,256)
                                                     const float* __restrict__ W,   // (8192,256)
                                                     const float* __restrict__ bias,
                                                     float* __restrict__ out) {     // (16,8192)
    __shared__ float zl[BATCH * 256];
    for (int t = threadIdx.x; t < BATCH * 256; t += 256) zl[t] = z[t];
    __syncthreads();
    const int m = blockIdx.x * 256 + threadIdx.x;
    const float* __restrict__ wr = W + (size_t)m * 256;
    float acc[BATCH];
    #pragma unroll
    for (int b = 0; b < BATCH; ++b) acc[b] = 0.f;
    for (int l = 0; l < 256; l += 4) {
        const float4 w4 = *reinterpret_cast<const float4*>(wr + l);
        #pragma unroll
        for (int b = 0; b < BATCH; ++b) {
            acc[b] += w4.x * zl[b * 256 + l]     + w4.y * zl[b * 256 + l + 1]
                    + w4.z * zl[b * 256 + l + 2] + w4.w * zl[b * 256 + l + 3];
        }
    }
    const float bm = bias[m];
    #pragma unroll
    for (int b = 0; b < BATCH; ++b) out[(size_t)b * 8192 + m] = acc[b] + bm;
}

// ---------------- host-side orchestration ----------------
extern "C" void kernel_launch(void* const* d_in, const int* in_sizes, int n_in,
                              void* d_out, int out_size, void* d_ws, size_t ws_size,
                              hipStream_t stream) {
    (void)in_sizes; (void)n_in; (void)out_size; (void)ws_size;

    const float* x = (const float*)d_in[0];
    const int* si[4] = {(const int*)d_in[1], (const int*)d_in[2],
                        (const int*)d_in[3], (const int*)d_in[4]};
    const int*   dcol[4]; const float* dval[4];
    const int*   ucol[4]; const float* uval[4];
    for (int i = 0; i < 4; ++i) {
        dcol[i] = (const int*)  d_in[5 + 6 * i + 1];
        dval[i] = (const float*)d_in[5 + 6 * i + 2];
        ucol[i] = (const int*)  d_in[5 + 6 * i + 4];
        uval[i] = (const float*)d_in[5 + 6 * i + 5];
    }
    const float *enW[4], *enb[4], *deW[4], *deb[4];
    for (int i = 0; i < 4; ++i) {
        enW[i] = (const float*)d_in[29 + 2 * i];
        enb[i] = (const float*)d_in[30 + 2 * i];
        deW[i] = (const float*)d_in[41 + 2 * i];
        deb[i] = (const float*)d_in[42 + 2 * i];
    }
    const float* fcW  = (const float*)d_in[37];
    const float* fcb  = (const float*)d_in[38];
    const float* dfcW = (const float*)d_in[39];
    const float* dfcb = (const float*)d_in[40];
    const float* outW = (const float*)d_in[49];
    const float* outb = (const float*)d_in[50];

    // workspace layout (floats): A | Bb | z | transposed weights
    float* ws = (float*)d_ws;
    float* A  = ws;
    float* Bb = A  + (size_t)BATCH * NN0 * 32;
    float* z  = Bb + (size_t)BATCH * NN0 * 32;
    float* wt_en0 = z + BATCH * 256;
    float* wt_en1 = wt_en0 + 27  * 32;
    float* wt_en2 = wt_en1 + 288 * 32;
    float* wt_en3 = wt_en2 + 288 * 32;
    float* wt_de0 = wt_en3 + 288 * 64;
    float* wt_de1 = wt_de0 + 576 * 64;
    float* wt_de2 = wt_de1 + 576 * 32;
    float* wt_de3 = wt_de2 + 288 * 32;

    float* out    = (float*)d_out;                    // (16, 32768, 3)
    float* out_z  = out + (size_t)BATCH * NN0 * 3;    // (16, 256)
    float* out_mu = out_z + BATCH * 256;              // (16, 256)

    // fused weight transposes (out_conv uses original layout, not transposed)
    {
        TA ta; int off = 0;
        auto add = [&](int j, const float* W, float* Wt, int CO, int K) {
            ta.d[j] = TD{W, Wt, CO, K, off}; off += CO * K;
        };
        add(0, enW[0], wt_en0, 32, 27);
        add(1, enW[1], wt_en1, 32, 288);
        add(2, enW[2], wt_en2, 32, 288);
        add(3, enW[3], wt_en3, 64, 288);
        add(4, deW[0], wt_de0, 64, 576);
        add(5, deW[1], wt_de1, 32, 576);
        add(6, deW[2], wt_de2, 32, 288);
        add(7, deW[3], wt_de3, 32, 288);
        ta.total = off;
        transpose_all<<<(off + 255) / 256, 256, 0, stream>>>(ta);
    }

    // ---------------- encoder ----------------
    conv0_v3<<<dim3(NN0 / 128, BATCH), 256, 0, stream>>>(x, si[0], wt_en0, enb[0], A, NN0);
    pool_kernel<32><<<(BATCH * NN1 * 8) / 256, 256, 0, stream>>>(A, dcol[0], dval[0], Bb, NN1, NN0);
    conv_v3<32, 32, true><<<dim3(NN1 / 128, BATCH), 256, 0, stream>>>(Bb, si[1], wt_en1, enb[1], A, NN1);
    pool_kernel<32><<<(BATCH * NN2 * 8) / 256, 256, 0, stream>>>(A, dcol[1], dval[1], Bb, NN2, NN1);
    conv_v3<32, 32, true><<<dim3(NN2 / 128, BATCH), 256, 0, stream>>>(Bb, si[2], wt_en2, enb[2], A, NN2);
    pool_kernel<32><<<(BATCH * NN3 * 8) / 256, 256, 0, stream>>>(A, dcol[2], dval[2], Bb, NN3, NN2);
    conv_v3<32, 64, true><<<dim3(NN3 / 64, BATCH), 256, 0, stream>>>(Bb, si[3], wt_en3, enb[3], A, NN3);
    pool_kernel<64><<<(BATCH * NN4 * 16) / 256, 256, 0, stream>>>(A, dcol[3], dval[3], Bb, NN4, NN3);

    // ---------------- latent ----------------
    fc_enc_kernel<<<256, 256, 0, stream>>>(Bb, fcW, fcb, z, out_z, out_mu);
    fc_dec_kernel<<<32, 256, 0, stream>>>(z, dfcW, dfcb, A);

    // ---------------- decoder ----------------
    pool_kernel<64><<<(BATCH * NN3 * 16) / 256, 256, 0, stream>>>(A, ucol[3], uval[3], Bb, NN3, NN4);
    conv_v3<64, 64, true><<<dim3(NN3 / 64, BATCH), 256, 0, stream>>>(Bb, si[3], wt_de0, deb[0], A, NN3);
    pool_kernel<64><<<(BATCH * NN2 * 16) / 256, 256, 0, stream>>>(A, ucol[2], uval[2], Bb, NN2, NN3);
    conv_v3<64, 32, true><<<dim3(NN2 / 128, BATCH), 256, 0, stream>>>(Bb, si[2], wt_de1, deb[1], A, NN2);
    pool_kernel<32><<<(BATCH * NN1 * 8) / 256, 256, 0, stream>>>(A, ucol[1], uval[1], Bb, NN1, NN2);
    conv_v3<32, 32, true><<<dim3(NN1 / 128, BATCH), 256, 0, stream>>>(Bb, si[1], wt_de2, deb[2], A, NN1);
    pool_kernel<32><<<(BATCH * NN0 * 8) / 256, 256, 0, stream>>>(A, ucol[0], uval[0], Bb, NN0, NN1);
    conv_v3<32, 32, true><<<dim3(NN0 / 128, BATCH), 256, 0, stream>>>(Bb, si[0], wt_de3, deb[3], A, NN0);

    // ---------------- output head ----------------
    out_conv_v3<<<dim3(NN0 / 256, BATCH), 256, 0, stream>>>(A, si[0], outW, outb, out, NN0);
}

// Round 4
// 753.770 us; speedup vs baseline: 1.3456x; 1.3456x over previous
//
#include <hip/hip_runtime.h>
#include <cstdint>
#include <cstddef>

#define BATCH 16

static constexpr int NN0 = 32768, NN1 = 8192, NN2 = 2048, NN3 = 512, NN4 = 128;

__device__ __forceinline__ float fast_elu(float a) {
    // exp(a)-1 via v_exp_f32; abs err ~1e-7 for a<0, far below harness tolerance
    return a > 0.f ? a : __expf(a) - 1.f;
}

// ---------------- fused weight transposes: W (CO,K) -> Wt (K,CO) ----------------
struct TD { const float* W; float* Wt; int CO, K, off; };
struct TA { TD d[8]; int total; };

__global__ __launch_bounds__(256) void transpose_all(TA a) {
    int i = blockIdx.x * 256 + threadIdx.x;
    if (i >= a.total) return;
    #pragma unroll
    for (int j = 0; j < 8; ++j) {
        const TD t = a.d[j];
        if (i >= t.off && i < t.off + t.CO * t.K) {
            int e = i - t.off, c = e / t.K, k = e - c * t.K;
            t.Wt[k * t.CO + c] = t.W[e];
            return;
        }
    }
}

// ---------------- conv0 v4: CIN=3, COUT=32 — registers only, scalar weights ----------
// thread = vertex; 27 gathered floats in VGPRs; weights via wave-uniform s_loads.
__global__ __launch_bounds__(256) void conv0_v4(const float* __restrict__ x,
                                                const int* __restrict__ idx,
                                                const float* __restrict__ Wt,   // (27,32)
                                                const float* __restrict__ bias,
                                                float* __restrict__ out,
                                                int N) {
    const int v = blockIdx.x * 256 + threadIdx.x;
    const int b = blockIdx.y;
    const float* __restrict__ xb = x + (size_t)b * N * 3;

    int nb[9];
    #pragma unroll
    for (int s = 0; s < 9; ++s) nb[s] = idx[(size_t)v * 9 + s];

    float g[27];
    #pragma unroll
    for (int s = 0; s < 9; ++s) {
        const float* __restrict__ p = xb + (size_t)nb[s] * 3;
        g[s * 3 + 0] = p[0]; g[s * 3 + 1] = p[1]; g[s * 3 + 2] = p[2];
    }

    float acc[32];
    #pragma unroll
    for (int c = 0; c < 32; ++c) acc[c] = bias[c];      // uniform s_loads

    #pragma unroll
    for (int k = 0; k < 27; ++k) {
        const float gk = g[k];
        const float* __restrict__ wr = Wt + k * 32;     // uniform address
        #pragma unroll
        for (int c = 0; c < 32; ++c) acc[c] += gk * wr[c];
    }

    float* __restrict__ o = out + ((size_t)b * N + v) * 32;
    #pragma unroll
    for (int q = 0; q < 8; ++q) {
        float4 t;
        t.x = fast_elu(acc[q * 4 + 0]);
        t.y = fast_elu(acc[q * 4 + 1]);
        t.z = fast_elu(acc[q * 4 + 2]);
        t.w = fast_elu(acc[q * 4 + 3]);
        *reinterpret_cast<float4*>(o + q * 4) = t;
    }
}

// ---------------- conv v3: lane=vertex, wave=16-channel group, W via scalar loads ----
template<int CIN, int COUT, bool ELU>
__global__ __launch_bounds__(256) void conv_v3(const float* __restrict__ x,
                                               const int* __restrict__ idx,
                                               const float* __restrict__ Wt,
                                               const float* __restrict__ bias,
                                               float* __restrict__ out,
                                               int N) {
    static_assert(COUT % 16 == 0, "COUT multiple of 16");
    constexpr int QG    = COUT / 16;
    static_assert(QG <= 4 && 4 % QG == 0, "QG in {1,2,4}");
    constexpr int VSETS = 4 / QG;
    constexpr int VPB   = 64 * VSETS;
    constexpr int GS    = CIN + 4;
    constexpr int CQ    = CIN / 4;

    __shared__ float g[VPB][GS];
    __shared__ int   nbr[VPB][9];

    const int b  = blockIdx.y;
    const int v0 = blockIdx.x * VPB;
    const float* __restrict__ xb = x + (size_t)b * N * CIN;

    for (int t = threadIdx.x; t < VPB * 9; t += 256)
        nbr[t / 9][t % 9] = idx[(size_t)v0 * 9 + t];

    const int wv   = __builtin_amdgcn_readfirstlane(threadIdx.x >> 6);
    const int lane = threadIdx.x & 63;
    const int vset = wv / QG;
    const int qg   = wv % QG;
    const int vloc = vset * 64 + lane;

    float4 acc[4];
    #pragma unroll
    for (int q = 0; q < 4; ++q) acc[q] = make_float4(0.f, 0.f, 0.f, 0.f);

    for (int s = 0; s < 9; ++s) {
        __syncthreads();
        constexpr int GSLOTS = VPB * CQ;
        static_assert(GSLOTS % 256 == 0, "staging divisibility");
        #pragma unroll
        for (int p = 0; p < GSLOTS / 256; ++p) {
            const int slot = p * 256 + threadIdx.x;
            const int v = slot / CQ, q = slot - v * CQ;
            const float4 t4 = *reinterpret_cast<const float4*>(
                xb + (size_t)nbr[v][s] * CIN + q * 4);
            *reinterpret_cast<float4*>(&g[v][q * 4]) = t4;
        }
        __syncthreads();

        const float* __restrict__ wbase = Wt + (size_t)s * CIN * COUT + qg * 16;
        #pragma unroll
        for (int k4 = 0; k4 < CQ; ++k4) {
            const float4 gv = *reinterpret_cast<const float4*>(&g[vloc][k4 * 4]);
            #pragma unroll
            for (int kk = 0; kk < 4; ++kk) {
                const float* __restrict__ wr = wbase + (size_t)(k4 * 4 + kk) * COUT;
                const float4 w0 = *reinterpret_cast<const float4*>(wr);
                const float4 w1 = *reinterpret_cast<const float4*>(wr + 4);
                const float4 w2 = *reinterpret_cast<const float4*>(wr + 8);
                const float4 w3 = *reinterpret_cast<const float4*>(wr + 12);
                const float gk = (kk == 0) ? gv.x : (kk == 1) ? gv.y : (kk == 2) ? gv.z : gv.w;
                acc[0].x += gk * w0.x; acc[0].y += gk * w0.y; acc[0].z += gk * w0.z; acc[0].w += gk * w0.w;
                acc[1].x += gk * w1.x; acc[1].y += gk * w1.y; acc[1].z += gk * w1.z; acc[1].w += gk * w1.w;
                acc[2].x += gk * w2.x; acc[2].y += gk * w2.y; acc[2].z += gk * w2.z; acc[2].w += gk * w2.w;
                acc[3].x += gk * w3.x; acc[3].y += gk * w3.y; acc[3].z += gk * w3.z; acc[3].w += gk * w3.w;
            }
        }
    }

    float* __restrict__ orow = out + ((size_t)b * N + v0 + vloc) * COUT + qg * 16;
    #pragma unroll
    for (int q = 0; q < 4; ++q) {
        const float4 bv = *reinterpret_cast<const float4*>(bias + qg * 16 + q * 4);
        float4 a = acc[q];
        a.x += bv.x; a.y += bv.y; a.z += bv.z; a.w += bv.w;
        if constexpr (ELU) {
            a.x = fast_elu(a.x);
            a.y = fast_elu(a.y);
            a.z = fast_elu(a.z);
            a.w = fast_elu(a.w);
        }
        *reinterpret_cast<float4*>(orow + q * 4) = a;
    }
}

// ---------------- final conv (CIN=32, COUT=3): W used untransposed (3,288) ----------------
__global__ __launch_bounds__(256) void out_conv_v3(const float* __restrict__ x,
                                                   const int* __restrict__ idx,
                                                   const float* __restrict__ W,   // (3,288)
                                                   const float* __restrict__ bias,
                                                   float* __restrict__ out,
                                                   int N) {
    constexpr int VPB = 256;
    constexpr int GS  = 36;
    __shared__ float g[VPB][GS];
    __shared__ int   nbr[VPB][9];

    const int b  = blockIdx.y;
    const int v0 = blockIdx.x * VPB;
    const float* __restrict__ xb = x + (size_t)b * N * 32;

    for (int t = threadIdx.x; t < VPB * 9; t += 256)
        nbr[t / 9][t % 9] = idx[(size_t)v0 * 9 + t];

    const int vloc = threadIdx.x;
    float a0 = 0.f, a1 = 0.f, a2 = 0.f;

    for (int s = 0; s < 9; ++s) {
        __syncthreads();
        #pragma unroll
        for (int p = 0; p < 8; ++p) {
            const int slot = p * 256 + threadIdx.x;
            const int v = slot / 8, q = slot - v * 8;
            const float4 t4 = *reinterpret_cast<const float4*>(
                xb + (size_t)nbr[v][s] * 32 + q * 4);
            *reinterpret_cast<float4*>(&g[v][q * 4]) = t4;
        }
        __syncthreads();
        #pragma unroll
        for (int k4 = 0; k4 < 8; ++k4) {
            const float4 gv = *reinterpret_cast<const float4*>(&g[vloc][k4 * 4]);
            const float4 w0 = *reinterpret_cast<const float4*>(W +   0 + s * 32 + k4 * 4);
            const float4 w1 = *reinterpret_cast<const float4*>(W + 288 + s * 32 + k4 * 4);
            const float4 w2 = *reinterpret_cast<const float4*>(W + 576 + s * 32 + k4 * 4);
            a0 += gv.x * w0.x + gv.y * w0.y + gv.z * w0.z + gv.w * w0.w;
            a1 += gv.x * w1.x + gv.y * w1.y + gv.z * w1.z + gv.w * w1.w;
            a2 += gv.x * w2.x + gv.y * w2.y + gv.z * w2.z + gv.w * w2.w;
        }
    }

    float* o = out + ((size_t)b * N + v0 + vloc) * 3;
    o[0] = a0 + bias[0]; o[1] = a1 + bias[1]; o[2] = a2 + bias[2];
}

// ---------------- pool: out[b,r,:] = sum_{j<3} val[3r+j] * x[b, col[3r+j], :] ----------------
template<int C>
__global__ __launch_bounds__(256) void pool_kernel(const float* __restrict__ x,
                                                   const int* __restrict__ col,
                                                   const float* __restrict__ val,
                                                   float* __restrict__ out,
                                                   int Nout, int Nin) {
    constexpr int CQ = C / 4;
    const int q = blockIdx.x * 256 + threadIdx.x;
    if (q >= BATCH * Nout * CQ) return;
    const int cq = q % CQ;
    const int r  = (q / CQ) % Nout;
    const int b  = q / (CQ * Nout);
    float ax = 0.f, ay = 0.f, az = 0.f, aw = 0.f;
    #pragma unroll
    for (int j = 0; j < 3; ++j) {
        const int   c0 = col[3 * r + j];
        const float vl = val[3 * r + j];
        const float4 xv = *reinterpret_cast<const float4*>(
            x + ((size_t)b * Nin + c0) * C + cq * 4);
        ax += vl * xv.x; ay += vl * xv.y; az += vl * xv.z; aw += vl * xv.w;
    }
    float4 o; o.x = ax; o.y = ay; o.z = az; o.w = aw;
    *reinterpret_cast<float4*>(out + ((size_t)b * Nout + r) * C + cq * 4) = o;
}

// ---------------- encoder FC: z = sigmoid(h @ fcW^T + fcb), h (16,8192) ----------------
__global__ __launch_bounds__(256) void fc_enc_kernel(const float* __restrict__ h,
                                                     const float* __restrict__ W,   // (256, 8192)
                                                     const float* __restrict__ bias,
                                                     float* __restrict__ z,
                                                     float* __restrict__ out_z,
                                                     float* __restrict__ out_mu) {
    const int l = blockIdx.x;
    const float* __restrict__ wr = W + (size_t)l * 8192;
    float acc[BATCH];
    #pragma unroll
    for (int b = 0; b < BATCH; ++b) acc[b] = 0.f;
    for (int k = threadIdx.x * 4; k < 8192; k += 256 * 4) {
        const float4 w4 = *reinterpret_cast<const float4*>(wr + k);
        #pragma unroll
        for (int b = 0; b < BATCH; ++b) {
            const float4 h4 = *reinterpret_cast<const float4*>(h + (size_t)b * 8192 + k);
            acc[b] += w4.x * h4.x + w4.y * h4.y + w4.z * h4.z + w4.w * h4.w;
        }
    }
    __shared__ float red[BATCH][4];
    const int wid = threadIdx.x >> 6, lane = threadIdx.x & 63;
    #pragma unroll
    for (int b = 0; b < BATCH; ++b) {
        float v = acc[b];
        for (int off = 32; off; off >>= 1) v += __shfl_down(v, off);
        if (lane == 0) red[b][wid] = v;
    }
    __syncthreads();
    if (threadIdx.x < BATCH) {
        const int b = threadIdx.x;
        float s = red[b][0] + red[b][1] + red[b][2] + red[b][3] + bias[l];
        s = 1.f / (1.f + expf(-s));
        z[b * 256 + l]      = s;
        out_z[b * 256 + l]  = s;
        out_mu[b * 256 + l] = s;
    }
}

// ---------------- decoder FC: h = z @ dfcW^T + dfcb -> (16, 8192) ----------------
__global__ __launch_bounds__(256) void fc_dec_kernel(const float* __restrict__ z,   // (16,256)
                                                     const float* __restrict__ W,   // (8192,256)
                                                     const float* __restrict__ bias,
                                                     float* __restrict__ out) {     // (16,8192)
    __shared__ float zl[BATCH * 256];
    for (int t = threadIdx.x; t < BATCH * 256; t += 256) zl[t] = z[t];
    __syncthreads();
    const int m = blockIdx.x * 256 + threadIdx.x;
    const float* __restrict__ wr = W + (size_t)m * 256;
    float acc[BATCH];
    #pragma unroll
    for (int b = 0; b < BATCH; ++b) acc[b] = 0.f;
    for (int l = 0; l < 256; l += 4) {
        const float4 w4 = *reinterpret_cast<const float4*>(wr + l);
        #pragma unroll
        for (int b = 0; b < BATCH; ++b) {
            acc[b] += w4.x * zl[b * 256 + l]     + w4.y * zl[b * 256 + l + 1]
                    + w4.z * zl[b * 256 + l + 2] + w4.w * zl[b * 256 + l + 3];
        }
    }
    const float bm = bias[m];
    #pragma unroll
    for (int b = 0; b < BATCH; ++b) out[(size_t)b * 8192 + m] = acc[b] + bm;
}

// ---------------- host-side orchestration ----------------
extern "C" void kernel_launch(void* const* d_in, const int* in_sizes, int n_in,
                              void* d_out, int out_size, void* d_ws, size_t ws_size,
                              hipStream_t stream) {
    (void)in_sizes; (void)n_in; (void)out_size; (void)ws_size;

    const float* x = (const float*)d_in[0];
    const int* si[4] = {(const int*)d_in[1], (const int*)d_in[2],
                        (const int*)d_in[3], (const int*)d_in[4]};
    const int*   dcol[4]; const float* dval[4];
    const int*   ucol[4]; const float* uval[4];
    for (int i = 0; i < 4; ++i) {
        dcol[i] = (const int*)  d_in[5 + 6 * i + 1];
        dval[i] = (const float*)d_in[5 + 6 * i + 2];
        ucol[i] = (const int*)  d_in[5 + 6 * i + 4];
        uval[i] = (const float*)d_in[5 + 6 * i + 5];
    }
    const float *enW[4], *enb[4], *deW[4], *deb[4];
    for (int i = 0; i < 4; ++i) {
        enW[i] = (const float*)d_in[29 + 2 * i];
        enb[i] = (const float*)d_in[30 + 2 * i];
        deW[i] = (const float*)d_in[41 + 2 * i];
        deb[i] = (const float*)d_in[42 + 2 * i];
    }
    const float* fcW  = (const float*)d_in[37];
    const float* fcb  = (const float*)d_in[38];
    const float* dfcW = (const float*)d_in[39];
    const float* dfcb = (const float*)d_in[40];
    const float* outW = (const float*)d_in[49];
    const float* outb = (const float*)d_in[50];

    // workspace layout (floats): A | Bb | z | transposed weights
    float* ws = (float*)d_ws;
    float* A  = ws;
    float* Bb = A  + (size_t)BATCH * NN0 * 32;
    float* z  = Bb + (size_t)BATCH * NN0 * 32;
    float* wt_en0 = z + BATCH * 256;
    float* wt_en1 = wt_en0 + 27  * 32;
    float* wt_en2 = wt_en1 + 288 * 32;
    float* wt_en3 = wt_en2 + 288 * 32;
    float* wt_de0 = wt_en3 + 288 * 64;
    float* wt_de1 = wt_de0 + 576 * 64;
    float* wt_de2 = wt_de1 + 576 * 32;
    float* wt_de3 = wt_de2 + 288 * 32;

    float* out    = (float*)d_out;                    // (16, 32768, 3)
    float* out_z  = out + (size_t)BATCH * NN0 * 3;    // (16, 256)
    float* out_mu = out_z + BATCH * 256;              // (16, 256)

    // fused weight transposes (out_conv uses original layout, not transposed)
    {
        TA ta; int off = 0;
        auto add = [&](int j, const float* W, float* Wt, int CO, int K) {
            ta.d[j] = TD{W, Wt, CO, K, off}; off += CO * K;
        };
        add(0, enW[0], wt_en0, 32, 27);
        add(1, enW[1], wt_en1, 32, 288);
        add(2, enW[2], wt_en2, 32, 288);
        add(3, enW[3], wt_en3, 64, 288);
        add(4, deW[0], wt_de0, 64, 576);
        add(5, deW[1], wt_de1, 32, 576);
        add(6, deW[2], wt_de2, 32, 288);
        add(7, deW[3], wt_de3, 32, 288);
        ta.total = off;
        transpose_all<<<(off + 255) / 256, 256, 0, stream>>>(ta);
    }

    // ---------------- encoder ----------------
    conv0_v4<<<dim3(NN0 / 256, BATCH), 256, 0, stream>>>(x, si[0], wt_en0, enb[0], A, NN0);
    pool_kernel<32><<<(BATCH * NN1 * 8) / 256, 256, 0, stream>>>(A, dcol[0], dval[0], Bb, NN1, NN0);
    conv_v3<32, 32, true><<<dim3(NN1 / 128, BATCH), 256, 0, stream>>>(Bb, si[1], wt_en1, enb[1], A, NN1);
    pool_kernel<32><<<(BATCH * NN2 * 8) / 256, 256, 0, stream>>>(A, dcol[1], dval[1], Bb, NN2, NN1);
    conv_v3<32, 32, true><<<dim3(NN2 / 128, BATCH), 256, 0, stream>>>(Bb, si[2], wt_en2, enb[2], A, NN2);
    pool_kernel<32><<<(BATCH * NN3 * 8) / 256, 256, 0, stream>>>(A, dcol[2], dval[2], Bb, NN3, NN2);
    conv_v3<32, 64, true><<<dim3(NN3 / 64, BATCH), 256, 0, stream>>>(Bb, si[3], wt_en3, enb[3], A, NN3);
    pool_kernel<64><<<(BATCH * NN4 * 16) / 256, 256, 0, stream>>>(A, dcol[3], dval[3], Bb, NN4, NN3);

    // ---------------- latent ----------------
    fc_enc_kernel<<<256, 256, 0, stream>>>(Bb, fcW, fcb, z, out_z, out_mu);
    fc_dec_kernel<<<32, 256, 0, stream>>>(z, dfcW, dfcb, A);

    // ---------------- decoder ----------------
    pool_kernel<64><<<(BATCH * NN3 * 16) / 256, 256, 0, stream>>>(A, ucol[3], uval[3], Bb, NN3, NN4);
    conv_v3<64, 64, true><<<dim3(NN3 / 64, BATCH), 256, 0, stream>>>(Bb, si[3], wt_de0, deb[0], A, NN3);
    pool_kernel<64><<<(BATCH * NN2 * 16) / 256, 256, 0, stream>>>(A, ucol[2], uval[2], Bb, NN2, NN3);
    conv_v3<64, 32, true><<<dim3(NN2 / 128, BATCH), 256, 0, stream>>>(Bb, si[2], wt_de1, deb[1], A, NN2);
    pool_kernel<32><<<(BATCH * NN1 * 8) / 256, 256, 0, stream>>>(A, ucol[1], uval[1], Bb, NN1, NN2);
    conv_v3<32, 32, true><<<dim3(NN1 / 128, BATCH), 256, 0, stream>>>(Bb, si[1], wt_de2, deb[2], A, NN1);
    pool_kernel<32><<<(BATCH * NN0 * 8) / 256, 256, 0, stream>>>(A, ucol[0], uval[0], Bb, NN0, NN1);
    conv_v3<32, 32, true><<<dim3(NN0 / 128, BATCH), 256, 0, stream>>>(Bb, si[0], wt_de3, deb[3], A, NN0);

    // ---------------- output head ----------------
    out_conv_v3<<<dim3(NN0 / 256, BATCH), 256, 0, stream>>>(A, si[0], outW, outb, out, NN0);
}